// Round 4
// baseline (423.885 us; speedup 1.0000x reference)
//
#include <hip/hip_runtime.h>
#include <math.h>

// Problem constants (match reference)
constexpr int N   = 1024;
constexpr int D   = 128;
constexpr int S   = 200;
constexpr int D2  = D / 2;            // float2 elements per row
constexpr int ND2 = N * D2;           // per-step noise stride in float2
constexpr int CHAIN_BLOCKS = (N * D2) / 256;   // 256 blocks cover all chains
constexpr int SEG = 8;                // k-segments, each block owns 25 steps
constexpr int L   = S / SEG;          // 25
constexpr int PF  = 5;                // prefetch batch (divides L and every k0)

// clang builtin vector types — required by __builtin_nontemporal_{load,store}
typedef float f2 __attribute__((ext_vector_type(2)));
typedef float f4 __attribute__((ext_vector_type(4)));

// One fused kernel:
//   blocks [0, SEG*CHAIN_BLOCKS): chain blocks. Block (seg, rb) recomputes the
//     x-prefix for steps 0..seg*L-1 (loads + 2 FMA/elem, no stores; redundant
//     reads hit L2/L3 since all segments stream the same early noise), then
//     emits steps seg*L .. seg*L+24 with nontemporal stores.
//     Exact same fmaf sequence as previous rounds -> bitwise identical output.
//   blocks [SEG*CHAIN_BLOCKS, +N): y/steps writer blocks (pure streaming).
// ~12 blocks/CU scheduled vs 1 block/CU for the old serial scan.
__global__ __launch_bounds__(256, 6) void langevin_seg_kernel(
    const f2* __restrict__ x0,
    const f4* __restrict__ y0,
    const f2* __restrict__ mean,
    const f2* __restrict__ var,
    const float* __restrict__ gammas,
    const f2* __restrict__ noise,   // [S][N][D2]
    f2* __restrict__ x_tot,         // [N][S][D2]
    f4* __restrict__ y_tot,         // [N][S][D/4]
    f2* __restrict__ outp,          // [N][S][D2]
    float* __restrict__ steps)      // [N][S]
{
    if (blockIdx.x >= SEG * CHAIN_BLOCKS) {
        // ---------- y / steps writer: one block per sample n ----------
        const int n   = blockIdx.x - SEG * CHAIN_BLOCKS;
        const int t   = threadIdx.x;
        const int col = t & 31;         // float4 column 0..31 (32*4 = 128 floats)
        const int r0  = t >> 5;         // row-group 0..7
        const f4  yv  = y0[(size_t)n * 32 + col];
        f4* yq = y_tot + (size_t)n * (S * 32);
        #pragma unroll
        for (int j = 0; j < S / 8; ++j) {
            const int k = r0 + j * 8;   // wave covers 2 rows = 1 KiB contiguous
            __builtin_nontemporal_store(yv, &yq[(size_t)k * 32 + col]);
        }
        if (t < S) steps[(size_t)n * S + t] = (float)t;
        return;
    }

    // ---------- chain block: (seg, rb) ----------
    __shared__ float sg[S];
    __shared__ float ss[S];
    for (int i = threadIdx.x; i < S; i += 256) {
        float g = gammas[i];
        sg[i] = g;
        ss[i] = sqrtf(2.0f * g);
    }
    __syncthreads();

    const int seg = blockIdx.x / CHAIN_BLOCKS;
    const int rb  = blockIdx.x % CHAIN_BLOCKS;
    const int k0  = seg * L;

    const int idx = rb * 256 + threadIdx.x;          // 0 .. N*D2-1
    const int n   = idx >> 6;
    const int dp  = idx & 63;

    f2 x        = x0[idx];
    const f2 m  = mean[dp];
    const f2 v  = var[dp];
    const float ivx = 1.0f / v.x;
    const float ivy = 1.0f / v.y;

    const f2* zp = noise + idx;

    // Preload first batch (steps 0..PF-1); cached loads (shared across segs).
    f2 zb[PF];
    #pragma unroll
    for (int i = 0; i < PF; ++i) zb[i] = zp[(size_t)i * ND2];

    // ----- prefix scan: steps 0 .. k0-1, x-update only, no stores -----
    // Next-batch loads are unconditional: max index = k0+PF-1 <= 179 < S.
    #pragma unroll 1
    for (int kb = 0; kb < k0; kb += PF) {
        f2 zn[PF];
        #pragma unroll
        for (int i = 0; i < PF; ++i)
            zn[i] = zp[(size_t)(kb + PF + i) * ND2];
        #pragma unroll
        for (int i = 0; i < PF; ++i) {
            const int k = kb + i;
            const float g = sg[k];
            const float s = ss[k];
            const float gx = g * ivx;
            const float gy = g * ivy;
            // identical op sequence to the emitting loop
            const float tox = fmaf(-gx, x.x - m.x, x.x);
            const float toy = fmaf(-gy, x.y - m.y, x.y);
            x.x = fmaf(s, zb[i].x, tox);
            x.y = fmaf(s, zb[i].y, toy);
        }
        #pragma unroll
        for (int i = 0; i < PF; ++i) zb[i] = zn[i];
    }
    // zb now holds z[k0 .. k0+PF-1]

    // ----- emit segment: steps k0 .. k0+L-1 -----
    const f2* zq = zp + (size_t)k0 * ND2;
    f2* xq = x_tot + (size_t)n * (S * D2) + (size_t)k0 * D2 + dp;
    f2* oq = outp  + (size_t)n * (S * D2) + (size_t)k0 * D2 + dp;

    #pragma unroll 1
    for (int kb = 0; kb < L; kb += PF) {
        f2 zn[PF];
        const bool more = (k0 + kb + PF) < S;   // only false on seg 7 last batch
        #pragma unroll
        for (int i = 0; i < PF; ++i)
            zn[i] = more ? zq[(size_t)(kb + PF + i) * ND2] : zb[i];
        #pragma unroll
        for (int i = 0; i < PF; ++i) {
            const int k = k0 + kb + i;
            const float g = sg[k];
            const float s = ss[k];
            const float gx = g * ivx;
            const float gy = g * ivy;

            const float tox = fmaf(-gx, x.x - m.x, x.x);
            const float toy = fmaf(-gy, x.y - m.y, x.y);
            x.x = fmaf(s, zb[i].x, tox);
            x.y = fmaf(s, zb[i].y, toy);
            const float tnx = fmaf(-gx, x.x - m.x, x.x);
            const float tny = fmaf(-gy, x.y - m.y, x.y);

            f2 o;
            o.x = tox - tnx;
            o.y = toy - tny;

            __builtin_nontemporal_store(x, &xq[(size_t)(kb + i) * D2]);
            __builtin_nontemporal_store(o, &oq[(size_t)(kb + i) * D2]);
        }
        #pragma unroll
        for (int i = 0; i < PF; ++i) zb[i] = zn[i];
    }
}

extern "C" void kernel_launch(void* const* d_in, const int* in_sizes, int n_in,
                              void* d_out, int out_size, void* d_ws, size_t ws_size,
                              hipStream_t stream)
{
    const float* x0     = (const float*)d_in[0];
    const float* y0     = (const float*)d_in[1];
    const float* mean   = (const float*)d_in[2];
    const float* var    = (const float*)d_in[3];
    const float* gammas = (const float*)d_in[4];
    const float* noise  = (const float*)d_in[5];

    float* x_tot = (float*)d_out;                       // N*S*D
    float* y_tot = x_tot + (size_t)N * S * D;           // N*S*D
    float* outp  = y_tot + (size_t)N * S * D;           // N*S*D
    float* steps = outp  + (size_t)N * S * D;           // N*S

    dim3 grid(SEG * CHAIN_BLOCKS + N);   // 2048 chain + 1024 writer blocks
    dim3 block(256);
    langevin_seg_kernel<<<grid, block, 0, stream>>>(
        (const f2*)x0, (const f4*)y0, (const f2*)mean, (const f2*)var,
        gammas, (const f2*)noise,
        (f2*)x_tot, (f4*)y_tot, (f2*)outp, steps);
}